// Round 3
// baseline (277.031 us; speedup 1.0000x reference)
//
#include <hip/hip_runtime.h>
#include <math.h>

// Problem constants (fixed by the reference).
#define Bsz 64
#define Ssz 14
#define Isz 32
#define Csz 10
#define Dsz 16
#define Nsz (Ssz*Ssz*Isz)   // 6272
#define EPSF 1e-9f

#define CH   640            // em chunk: n's per block (== block size); 640 % 32 == 0
#define NCH  10             // chunks; chunk 9 has 512 valid n
#define MCH  3136           // moment-kernel chunk (2 per b); 3136 % 32 == 0
#define MROW 72             // moment row stride (floats), 69 used
#define PRMS 36             // prm row stride: mean16 | invd16 | K | pad
#define BC   (Bsz*Csz)      // 640

// ---------------------------------------------------------------------------
// DPP wave64 sum: row_shr 1/2/4/8 then row_bcast 15/31. Total lands in lane 63.
// VALU-pipe only (no LDS traffic). Validated round 1.
// ---------------------------------------------------------------------------
template<int CTRL, int RMASK>
__device__ __forceinline__ float dpp_add(float x) {
    int y = __builtin_amdgcn_update_dpp(0, __float_as_int(x), CTRL, RMASK, 0xf, true);
    return x + __int_as_float(y);
}
__device__ __forceinline__ float wave_sum64(float x) {
    x = dpp_add<0x111, 0xf>(x);   // row_shr:1
    x = dpp_add<0x112, 0xf>(x);   // row_shr:2
    x = dpp_add<0x114, 0xf>(x);   // row_shr:4
    x = dpp_add<0x118, 0xf>(x);   // row_shr:8
    x = dpp_add<0x142, 0xa>(x);   // row_bcast:15
    x = dpp_add<0x143, 0xc>(x);   // row_bcast:31 -> lane63 = total
    return x;
}

// ---------------------------------------------------------------------------
// mom_kernel: iteration-0 class-independent per-i pose moments (validated r1),
// output via global atomics into a single zeroed slab partM[B][32][MROW].
// Moment layout per i: [0]=S0 [1..16]=Sp [17..56]=Spp(pr-major, pairs k<=k')
//                      [57..60]=Sh [61..64]=Sw [65]=Sch [66]=Scw [67]=Shh [68]=Sww
// ---------------------------------------------------------------------------
__global__ __launch_bounds__(640) void mom_kernel(
    const float* __restrict__ pose,     // [B][N][16]
    const float* __restrict__ act,      // [B][N]
    float* __restrict__ partM)          // [B][32][MROW]  (zeroed by host memset)
{
    const int b = blockIdx.x, mch = blockIdx.y;
    const int tid = threadIdx.x, lane = tid & 63;

    __shared__ float Macc[32][73];      // stride 73 -> conflict-free

    float s[69];
#pragma unroll
    for (int j = 0; j < 69; ++j) s[j] = 0.f;

    const float* poseb = pose + (size_t)b*Nsz*Dsz;
    const float* actb  = act  + (size_t)b*Nsz;
    const int base = mch*MCH;

    for (int k = 0; k < MCH; k += 640) {
        const int nl = k + tid;
        if (nl < MCH) {
            const int n = base + nl;    // i = n&31 = tid&31 (all strides %32==0)
            const float4* pp = reinterpret_cast<const float4*>(poseb + (size_t)n*Dsz);
            float4 a0 = pp[0], a1 = pp[1], a2 = pp[2], a3 = pp[3];
            float p[16] = {a0.x,a0.y,a0.z,a0.w, a1.x,a1.y,a1.z,a1.w,
                           a2.x,a2.y,a2.z,a2.w, a3.x,a3.y,a3.z,a3.w};
            const int hw = n >> 5, wc = hw % Ssz, hr = hw / Ssz;
            const float chh = (hr+0.5f)*(1.f/Ssz), cww = (wc+0.5f)*(1.f/Ssz);
            const float wgt = actb[n]*(1.f/Csz);
            s[0] += wgt;
            float wp[16];
#pragma unroll
            for (int j = 0; j < 16; ++j) { wp[j] = wgt*p[j]; s[1+j] += wp[j]; }
            int t = 17;
#pragma unroll
            for (int pr = 0; pr < 4; ++pr)
#pragma unroll
                for (int k1 = 0; k1 < 4; ++k1)
#pragma unroll
                    for (int k2 = k1; k2 < 4; ++k2)
                        s[t++] += wp[pr*4+k1]*p[pr*4+k2];
            const float wch = wgt*chh, wcw = wgt*cww;
#pragma unroll
            for (int j = 0; j < 4; ++j) { s[57+j] += wch*p[j]; s[61+j] += wcw*p[j]; }
            s[65] += wch; s[66] += wcw; s[67] += wch*chh; s[68] += wcw*cww;
        }
    }
    // lane and lane+32 share the same i -> fold
#pragma unroll
    for (int j = 0; j < 69; ++j) s[j] += __shfl_xor(s[j], 32);

    for (int t = tid; t < 32*73; t += 640) (&Macc[0][0])[t] = 0.f;
    __syncthreads();
    if (lane < 32) {
#pragma unroll
        for (int j = 0; j < 69; ++j) atomicAdd(&Macc[lane][j], s[j]);
    }
    __syncthreads();
    for (int t = tid; t < 32*MROW; t += 640) {
        const int i = t / MROW, j = t - i*MROW;
        if (j < 69) atomicAdd(&partM[(size_t)b*(32*MROW) + t], Macc[i][j]);
    }
}

// ---------------------------------------------------------------------------
// em_kernel<FIRST>: in-kernel finalize (FIRST: W-transform of moments; else:
// reduce class partials) -> prm in LDS; then Z (wave-per-class zz, W in
// registers, prm in SGPRs via readlane), S (thread-per-n softmax), M
// (wave-per-class weighted sums, DPP reduce) -> partOut[NCH][33][B*C].
// ---------------------------------------------------------------------------
template<bool FIRST>
__global__ __launch_bounds__(640, 5) void em_kernel(
    const float* __restrict__ pose, const float* __restrict__ act,
    const float* __restrict__ w, const float* __restrict__ beta_v,
    const float* __restrict__ beta_a, const float* __restrict__ partIn,
    float* __restrict__ partOut, float inv_temp_prev)
{
    const int b = blockIdx.x, chunk = blockIdx.y;
    const int tid = threadIdx.x, wv_ = tid >> 6, lane = tid & 63;

    __shared__ float Wm[FIRST ? Csz*Isz*17 : 1]; // stride 17 -> conflict-free (em1 only)
    __shared__ float U2[Csz*CH];                 // Mr/Sv staging, then zz/rr
    __shared__ float prm[Csz][PRMS];
    __shared__ float pl[Csz*Dsz];
    __shared__ float s0sh;

    // ---- stage ----
    if (FIRST) {
        for (int t = tid; t < Csz*Isz*Dsz; t += 640) {
            const int cc = t >> 9, rem = t & 511, i = rem >> 4, q = rem & 15;
            Wm[cc*(Isz*17) + i*17 + q] = w[(i*Csz + cc)*Dsz + q];
        }
        for (int t = tid; t < 32*MROW; t += 640) {      // Mr stride 73 in U2
            const int i = t / MROW, j = t - i*MROW;
            U2[i*73 + j] = partIn[(size_t)b*(32*MROW) + t];
        }
    } else {
        if (tid < Csz*33) {                              // Sv[c][33] in U2 (stride 34)
            const int c2 = tid / 33, j = tid - c2*33;
            float sacc = 0.f;
            const float* pb = partIn + (size_t)j*BC + b*Csz + c2;
            for (int ch = 0; ch < NCH; ++ch) sacc += pb[(size_t)ch*33*BC];
            U2[c2*34 + j] = sacc;
        }
    }
    __syncthreads();

    // ---- finalize -> prm {mean16, invd16}, pl {log std} ----
    if (tid < Csz*Dsz) {
        const int c = tid >> 4, d = tid & 15;
        if (FIRST) {
            const int pr = d >> 2, r = d & 3;
            float S0 = 0.f, S1 = 0.f, S2 = 0.f;
            for (int i = 0; i < 32; ++i) {
                const float* Mi = U2 + i*73;
                const float* Wi = Wm + c*(Isz*17) + i*17;
                S0 += Mi[0];
                const float w0 = Wi[r], w1 = Wi[4+r], w2 = Wi[8+r], w3 = Wi[12+r];
                const float* M1 = Mi + 1 + pr*4;
                S1 += w0*M1[0] + w1*M1[1] + w2*M1[2] + w3*M1[3];
                const float* Q = Mi + 17 + pr*10;
                S2 += w0*w0*Q[0] + w1*w1*Q[4] + w2*w2*Q[7] + w3*w3*Q[9]
                    + 2.f*(w0*w1*Q[1] + w0*w2*Q[2] + w0*w3*Q[3]
                         + w1*w2*Q[5] + w1*w3*Q[6] + w2*w3*Q[8]);
                if (d == 0) {
                    S1 += Mi[65];
                    S2 += 2.f*(w0*Mi[57] + w1*Mi[58] + w2*Mi[59] + w3*Mi[60]) + Mi[67];
                } else if (d == 1) {
                    S1 += Mi[66];
                    S2 += 2.f*(w0*Mi[61] + w1*Mi[62] + w2*Mi[63] + w3*Mi[64]) + Mi[68];
                }
            }
            const float mean = S1 / S0;
            const float var = fmaxf(S2/S0 - mean*mean, 0.f);
            prm[c][d]    = mean;
            prm[c][16+d] = 1.f/(2.f*var + EPSF);
            pl[tid]      = __logf(sqrtf(var) + EPSF);
            if (tid == 0) s0sh = S0;
        } else {
            const float S0 = U2[c*34];
            const float mn = U2[c*34 + 1 + d] / S0;
            const float var = fmaxf(U2[c*34 + 17 + d]/S0 - mn*mn, 0.f);
            prm[c][d]    = mn;
            prm[c][16+d] = 1.f/(2.f*var + EPSF);
            pl[tid]      = __logf(sqrtf(var) + EPSF);
        }
    }
    __syncthreads();
    if (tid < Csz) {
        float sumlog = 0.f;
#pragma unroll
        for (int d = 0; d < 16; ++d) sumlog += pl[tid*16 + d];
        const float S0 = FIRST ? s0sh : U2[tid*34];
        const float cost = S0*(16.f*beta_v[tid] + sumlog);
        const float oact = 1.f/(1.f + __expf(-inv_temp_prev*(beta_a[tid] - cost)));
        prm[tid][32] = __logf(oact + EPSF) - sumlog;    // K
    }
    __syncthreads();

    // ---- hoist: W[i=lane&31][c=wave] into VGPRs; prm[c] into SGPRs ----
    const int c = wv_;
    float W16[16];
    if (FIRST) {
#pragma unroll
        for (int j = 0; j < 16; ++j) W16[j] = Wm[c*(Isz*17) + (lane & 31)*17 + j];
    } else {
        const float4* wp = reinterpret_cast<const float4*>(
            w + ((size_t)(lane & 31)*Csz + c)*Dsz);
        float4 q0 = wp[0], q1 = wp[1], q2 = wp[2], q3 = wp[3];
        W16[0]=q0.x; W16[1]=q0.y; W16[2]=q0.z; W16[3]=q0.w;
        W16[4]=q1.x; W16[5]=q1.y; W16[6]=q1.z; W16[7]=q1.w;
        W16[8]=q2.x; W16[9]=q2.y; W16[10]=q2.z; W16[11]=q2.w;
        W16[12]=q3.x; W16[13]=q3.y; W16[14]=q3.z; W16[15]=q3.w;
    }
    const float pv = (lane < 33) ? prm[c][lane] : 0.f;
    const int pvi = __float_as_int(pv);
    float m_s[16], g_s[16];
#pragma unroll
    for (int d = 0; d < 16; ++d) {
        m_s[d] = __int_as_float(__builtin_amdgcn_readlane(pvi, d));
        g_s[d] = __int_as_float(__builtin_amdgcn_readlane(pvi, 16 + d));
    }
    const float K_s = __int_as_float(__builtin_amdgcn_readlane(pvi, 32));

    const int base = chunk*CH;
    const float* poseb = pose + (size_t)b*Nsz*Dsz;

    // ---- Z: wave-per-class zz -> U2[c][nl] (overwrites dead staging) ----
    for (int k = 0; k < CH; k += 64) {
        const int n = base + k + lane;
        if (n < Nsz) {
            const float4* pp = reinterpret_cast<const float4*>(poseb + (size_t)n*Dsz);
            float4 a0 = pp[0], a1 = pp[1], a2 = pp[2], a3 = pp[3];
            float p[16] = {a0.x,a0.y,a0.z,a0.w, a1.x,a1.y,a1.z,a1.w,
                           a2.x,a2.y,a2.z,a2.w, a3.x,a3.y,a3.z,a3.w};
            const int hw = n >> 5, wc2 = hw % Ssz, hr2 = hw / Ssz;
            const float chh = (hr2+0.5f)*(1.f/Ssz), cww = (wc2+0.5f)*(1.f/Ssz);
            float quad = 0.f;
#pragma unroll
            for (int pr = 0; pr < 4; ++pr) {
#pragma unroll
                for (int r = 0; r < 4; ++r) {
                    float vvv = p[pr*4]*W16[r] + p[pr*4+1]*W16[4+r]
                              + p[pr*4+2]*W16[8+r] + p[pr*4+3]*W16[12+r];
                    if (pr == 0 && r == 0) vvv += chh;
                    if (pr == 0 && r == 1) vvv += cww;
                    const float dv = vvv - m_s[pr*4+r];
                    quad += dv*dv*g_s[pr*4+r];
                }
            }
            U2[c*CH + k + lane] = K_s - quad;
        }
    }
    __syncthreads();

    // ---- S: thread-per-n softmax across classes, rr in place ----
    {
        const int n = base + tid;
        if (n < Nsz) {
            float z[Csz];
#pragma unroll
            for (int cc = 0; cc < Csz; ++cc) z[cc] = U2[cc*CH + tid];
            float zmax = z[0];
#pragma unroll
            for (int cc = 1; cc < Csz; ++cc) zmax = fmaxf(zmax, z[cc]);
            float zsum = 0.f;
#pragma unroll
            for (int cc = 0; cc < Csz; ++cc) { z[cc] = __expf(z[cc] - zmax); zsum += z[cc]; }
            const float sc = __fdividef(act[(size_t)b*Nsz + n], zsum);
#pragma unroll
            for (int cc = 0; cc < Csz; ++cc) U2[cc*CH + tid] = z[cc]*sc;
        }
    }
    __syncthreads();

    // ---- M: wave-per-class weighted sums (W16 reused), DPP reduce ----
    float s0 = 0.f, s1[16], s2[16];
#pragma unroll
    for (int d = 0; d < 16; ++d) { s1[d] = 0.f; s2[d] = 0.f; }
    for (int k = 0; k < CH; k += 64) {
        const int n = base + k + lane;
        if (n < Nsz) {
            const float4* pp = reinterpret_cast<const float4*>(poseb + (size_t)n*Dsz);
            const int hw = n >> 5, wc2 = hw % Ssz, hr2 = hw / Ssz;
            const float chh = (hr2+0.5f)*(1.f/Ssz), cww = (wc2+0.5f)*(1.f/Ssz);
            const float wgt = U2[c*CH + k + lane];
            s0 += wgt;
#pragma unroll
            for (int pr = 0; pr < 4; ++pr) {
                const float4 pvv = pp[pr];
#pragma unroll
                for (int r = 0; r < 4; ++r) {
                    float vvv = pvv.x*W16[r] + pvv.y*W16[4+r]
                              + pvv.z*W16[8+r] + pvv.w*W16[12+r];
                    if (pr == 0 && r == 0) vvv += chh;
                    if (pr == 0 && r == 1) vvv += cww;
                    const float wvv = wgt*vvv;
                    s1[pr*4+r] += wvv;
                    s2[pr*4+r] += wvv*vvv;
                }
            }
        }
    }
    s0 = wave_sum64(s0);
#pragma unroll
    for (int d = 0; d < 16; ++d) { s1[d] = wave_sum64(s1[d]); s2[d] = wave_sum64(s2[d]); }
    if (lane == 63) {
        float* pt = partOut + (size_t)chunk*33*BC + b*Csz + c;
        pt[0] = s0;
#pragma unroll
        for (int d = 0; d < 16; ++d) {
            pt[(size_t)(1+d)*BC]  = s1[d];
            pt[(size_t)(17+d)*BC] = s2[d];
        }
    }
}

// ---------------------------------------------------------------------------
// fin_kernel: thread per (b,c): reduce partials over chunks (coalesced),
// compute mean + o_act (inv_temp=3), write outputs. Validated round 1.
// ---------------------------------------------------------------------------
__global__ __launch_bounds__(64) void fin_kernel(
    const float* __restrict__ partC, const float* __restrict__ beta_v,
    const float* __restrict__ beta_a, float* __restrict__ out, float inv_temp)
{
    const int bc = blockIdx.x*64 + threadIdx.x;   // grid exact: 640 threads
    const int c = bc % Csz;
    float S[33];
#pragma unroll
    for (int j = 0; j < 33; ++j) S[j] = 0.f;
    for (int ch = 0; ch < NCH; ++ch) {
        const float* pb = partC + (size_t)ch*33*BC + bc;
#pragma unroll
        for (int j = 0; j < 33; ++j) S[j] += pb[(size_t)j*BC];
    }
    const float S0 = S[0], rS0 = 1.f/S0;
    float sumlog = 0.f;
#pragma unroll
    for (int d = 0; d < 16; ++d) {
        const float mn = S[1+d]*rS0;
        const float var = fmaxf(S[17+d]*rS0 - mn*mn, 0.f);
        out[(size_t)bc*Dsz + d] = mn;
        sumlog += __logf(sqrtf(var) + EPSF);
    }
    const float cost = S0*(16.f*beta_v[c] + sumlog);
    out[(size_t)Bsz*Csz*Dsz + bc] = 1.f/(1.f + __expf(-inv_temp*(beta_a[c] - cost)));
}

// ---------------------------------------------------------------------------
// 5 dispatches: memset -> mom -> EM1(fin0+Z/S/M) -> EM2(finC+Z/S/M) -> FIN.
// Workspace: regA/regB = 211200 floats each (1.69 MB total, proven budget).
// partM (147456 fl) lives in regA; partC = regB; partC2 aliases regA (partM
// is dead once EM1 completes).
// ---------------------------------------------------------------------------
extern "C" void kernel_launch(void* const* d_in, const int* in_sizes, int n_in,
                              void* d_out, int out_size, void* d_ws, size_t ws_size,
                              hipStream_t stream)
{
    (void)in_sizes; (void)n_in; (void)out_size; (void)ws_size;
    const float* pose = (const float*)d_in[0];
    const float* act  = (const float*)d_in[1];
    const float* w    = (const float*)d_in[2];
    const float* bv   = (const float*)d_in[3];
    const float* ba   = (const float*)d_in[4];
    float* out = (float*)d_out;

    float* regA = (float*)d_ws;                        // 211200 floats
    float* regB = regA + (size_t)NCH*33*BC;            // 211200 floats
    float* partM  = regA;                              // [64][32][72] = 147456 fl
    float* partC  = regB;                              // [10][33][640]
    float* partC2 = regA;                              // aliases partM (dead)

    hipMemsetAsync(partM, 0, (size_t)Bsz*32*MROW*sizeof(float), stream);
    mom_kernel      <<<dim3(Bsz, 2),   640, 0, stream>>>(pose, act, partM);
    em_kernel<true> <<<dim3(Bsz, NCH), 640, 0, stream>>>(pose, act, w, bv, ba, partM, partC, 1.0f);
    em_kernel<false><<<dim3(Bsz, NCH), 640, 0, stream>>>(pose, act, w, bv, ba, partC, partC2, 2.0f);
    fin_kernel      <<<NCH,             64, 0, stream>>>(partC2, bv, ba, out, 3.0f);
}

// Round 4
// 249.694 us; speedup vs baseline: 1.1095x; 1.1095x over previous
//
#include <hip/hip_runtime.h>
#include <math.h>

// Problem constants (fixed by the reference).
#define Bsz 64
#define Ssz 14
#define Isz 32
#define Csz 10
#define Dsz 16
#define Nsz (Ssz*Ssz*Isz)   // 6272
#define EPSF 1e-9f

#define CH   640            // em chunk: n's per block (== block size); 640 % 32 == 0
#define NCH  10             // chunks; chunk 9 has 512 valid n
#define MCH  3136           // moment-kernel chunk (2 per b); 3136 % 32 == 0
#define MROW 72             // moment row stride (floats), 69 used
#define PRMS 36             // prm row stride: mean16 | invd16 | K | pad (rows 16B-aligned)
#define BC   (Bsz*Csz)      // 640

// ---------------------------------------------------------------------------
// DPP wave64 sum: row_shr 1/2/4/8 then row_bcast 15/31. Total lands in lane 63.
// VALU-pipe only (no LDS traffic). Validated rounds 1/3.
// ---------------------------------------------------------------------------
template<int CTRL, int RMASK>
__device__ __forceinline__ float dpp_add(float x) {
    int y = __builtin_amdgcn_update_dpp(0, __float_as_int(x), CTRL, RMASK, 0xf, true);
    return x + __int_as_float(y);
}
__device__ __forceinline__ float wave_sum64(float x) {
    x = dpp_add<0x111, 0xf>(x);   // row_shr:1
    x = dpp_add<0x112, 0xf>(x);   // row_shr:2
    x = dpp_add<0x114, 0xf>(x);   // row_shr:4
    x = dpp_add<0x118, 0xf>(x);   // row_shr:8
    x = dpp_add<0x142, 0xa>(x);   // row_bcast:15
    x = dpp_add<0x143, 0xc>(x);   // row_bcast:31 -> lane63 = total
    return x;
}

// ---------------------------------------------------------------------------
// mom_kernel: iteration-0 class-independent per-i pose moments (validated r3):
// global atomics into a zeroed slab partM[B][32][MROW].
// Moment layout per i: [0]=S0 [1..16]=Sp [17..56]=Spp(pr-major, pairs k<=k')
//                      [57..60]=Sh [61..64]=Sw [65]=Sch [66]=Scw [67]=Shh [68]=Sww
// ---------------------------------------------------------------------------
__global__ __launch_bounds__(640) void mom_kernel(
    const float* __restrict__ pose,     // [B][N][16]
    const float* __restrict__ act,      // [B][N]
    float* __restrict__ partM)          // [B][32][MROW]  (zeroed by host memset)
{
    const int b = blockIdx.x, mch = blockIdx.y;
    const int tid = threadIdx.x, lane = tid & 63;

    __shared__ float Macc[32][73];      // stride 73 -> conflict-free

    float s[69];
#pragma unroll
    for (int j = 0; j < 69; ++j) s[j] = 0.f;

    const float* poseb = pose + (size_t)b*Nsz*Dsz;
    const float* actb  = act  + (size_t)b*Nsz;
    const int base = mch*MCH;

    for (int k = 0; k < MCH; k += 640) {
        const int nl = k + tid;
        if (nl < MCH) {
            const int n = base + nl;    // i = n&31 = tid&31 (all strides %32==0)
            const float4* pp = reinterpret_cast<const float4*>(poseb + (size_t)n*Dsz);
            float4 a0 = pp[0], a1 = pp[1], a2 = pp[2], a3 = pp[3];
            float p[16] = {a0.x,a0.y,a0.z,a0.w, a1.x,a1.y,a1.z,a1.w,
                           a2.x,a2.y,a2.z,a2.w, a3.x,a3.y,a3.z,a3.w};
            const int hw = n >> 5, wc = hw % Ssz, hr = hw / Ssz;
            const float chh = (hr+0.5f)*(1.f/Ssz), cww = (wc+0.5f)*(1.f/Ssz);
            const float wgt = actb[n]*(1.f/Csz);
            s[0] += wgt;
            float wp[16];
#pragma unroll
            for (int j = 0; j < 16; ++j) { wp[j] = wgt*p[j]; s[1+j] += wp[j]; }
            int t = 17;
#pragma unroll
            for (int pr = 0; pr < 4; ++pr)
#pragma unroll
                for (int k1 = 0; k1 < 4; ++k1)
#pragma unroll
                    for (int k2 = k1; k2 < 4; ++k2)
                        s[t++] += wp[pr*4+k1]*p[pr*4+k2];
            const float wch = wgt*chh, wcw = wgt*cww;
#pragma unroll
            for (int j = 0; j < 4; ++j) { s[57+j] += wch*p[j]; s[61+j] += wcw*p[j]; }
            s[65] += wch; s[66] += wcw; s[67] += wch*chh; s[68] += wcw*cww;
        }
    }
#pragma unroll
    for (int j = 0; j < 69; ++j) s[j] += __shfl_xor(s[j], 32);   // fold lane<->lane+32

    for (int t = tid; t < 32*73; t += 640) (&Macc[0][0])[t] = 0.f;
    __syncthreads();
    if (lane < 32) {
#pragma unroll
        for (int j = 0; j < 69; ++j) atomicAdd(&Macc[lane][j], s[j]);
    }
    __syncthreads();
    for (int t = tid; t < 32*MROW; t += 640) {
        const int i = t / MROW, j = t - i*MROW;
        if (j < 69) atomicAdd(&partM[(size_t)b*(32*MROW) + t], Macc[i][j]);
    }
}

// ---------------------------------------------------------------------------
// em_kernel<FIRST>: fused finalize -> prm in LDS, then round-1's validated
// E (thread-per-n) and M (wave-per-class, W16 hoisted at M start, DPP).
// No arrays kept live across __syncthreads; plain launch_bounds(640) so the
// allocator is free (round-3's (640,5) + cross-phase W16 caused 21MB of
// scratch spills).
// ---------------------------------------------------------------------------
template<bool FIRST>
__global__ __launch_bounds__(640) void em_kernel(
    const float* __restrict__ pose, const float* __restrict__ act,
    const float* __restrict__ w, const float* __restrict__ beta_v,
    const float* __restrict__ beta_a, const float* __restrict__ partIn,
    float* __restrict__ partOut, float inv_temp_prev)
{
    const int b = blockIdx.x, chunk = blockIdx.y;
    const int tid = threadIdx.x, wv_ = tid >> 6, lane = tid & 63;

    __shared__ float Wm[Csz][Isz*17];   // 21760 B, stride 17 -> conflict-free
    __shared__ float U2[Csz*CH];        // 25600 B: Mr/Sv staging, then rr
    __shared__ float prm[Csz][PRMS];    // mean16 | invd16 | K
    __shared__ float pl[Csz*Dsz];
    __shared__ float s0sh;

    // ---- stage W (needed by fin0, E, M) ----
    for (int t = tid; t < Csz*Isz*Dsz; t += 640) {
        const int cc = t >> 9, rem = t & 511, i = rem >> 4, q = rem & 15;
        Wm[cc][i*17 + q] = w[(i*Csz + cc)*Dsz + q];
    }
    // ---- stage prev-iteration partials into U2 ----
    if (FIRST) {
        for (int t = tid; t < 32*MROW; t += 640) {      // Mr stride 73 in U2
            const int i = t / MROW, j = t - i*MROW;
            U2[i*73 + j] = partIn[(size_t)b*(32*MROW) + t];
        }
    } else {
        if (tid < Csz*33) {                              // Sv[c][33] stride 34
            const int c2 = tid / 33, j = tid - c2*33;
            float sacc = 0.f;
            const float* pb = partIn + (size_t)j*BC + b*Csz + c2;
            for (int ch = 0; ch < NCH; ++ch) sacc += pb[(size_t)ch*33*BC];
            U2[c2*34 + j] = sacc;
        }
    }
    __syncthreads();

    // ---- finalize -> prm {mean16, invd16}, pl {log std} (validated r3) ----
    if (tid < Csz*Dsz) {
        const int c = tid >> 4, d = tid & 15;
        if (FIRST) {
            const int pr = d >> 2, r = d & 3;
            float S0 = 0.f, S1 = 0.f, S2 = 0.f;
            for (int i = 0; i < 32; ++i) {
                const float* Mi = U2 + i*73;
                const float* Wi = &Wm[c][i*17];
                S0 += Mi[0];
                const float w0 = Wi[r], w1 = Wi[4+r], w2 = Wi[8+r], w3 = Wi[12+r];
                const float* M1 = Mi + 1 + pr*4;
                S1 += w0*M1[0] + w1*M1[1] + w2*M1[2] + w3*M1[3];
                const float* Q = Mi + 17 + pr*10;
                S2 += w0*w0*Q[0] + w1*w1*Q[4] + w2*w2*Q[7] + w3*w3*Q[9]
                    + 2.f*(w0*w1*Q[1] + w0*w2*Q[2] + w0*w3*Q[3]
                         + w1*w2*Q[5] + w1*w3*Q[6] + w2*w3*Q[8]);
                if (d == 0) {
                    S1 += Mi[65];
                    S2 += 2.f*(w0*Mi[57] + w1*Mi[58] + w2*Mi[59] + w3*Mi[60]) + Mi[67];
                } else if (d == 1) {
                    S1 += Mi[66];
                    S2 += 2.f*(w0*Mi[61] + w1*Mi[62] + w2*Mi[63] + w3*Mi[64]) + Mi[68];
                }
            }
            const float mean = S1 / S0;
            const float var = fmaxf(S2/S0 - mean*mean, 0.f);
            prm[c][d]    = mean;
            prm[c][16+d] = 1.f/(2.f*var + EPSF);
            pl[tid]      = __logf(sqrtf(var) + EPSF);
            if (tid == 0) s0sh = S0;
        } else {
            const float S0 = U2[c*34];
            const float mn = U2[c*34 + 1 + d] / S0;
            const float var = fmaxf(U2[c*34 + 17 + d]/S0 - mn*mn, 0.f);
            prm[c][d]    = mn;
            prm[c][16+d] = 1.f/(2.f*var + EPSF);
            pl[tid]      = __logf(sqrtf(var) + EPSF);
        }
    }
    __syncthreads();
    if (tid < Csz) {
        float sumlog = 0.f;
#pragma unroll
        for (int d = 0; d < 16; ++d) sumlog += pl[tid*16 + d];
        const float S0 = FIRST ? s0sh : U2[tid*34];
        const float cost = S0*(16.f*beta_v[tid] + sumlog);
        const float oact = 1.f/(1.f + __expf(-inv_temp_prev*(beta_a[tid] - cost)));
        prm[tid][32] = __logf(oact + EPSF) - sumlog;    // K
    }
    __syncthreads();

    const int base = chunk*CH;
    const float* poseb = pose + (size_t)b*Nsz*Dsz;

    // ---- E: one n per thread (round-1 structure; prm via uniform float4) ----
    {
        const int n = base + tid;
        if (n < Nsz) {
            const float4* pp = reinterpret_cast<const float4*>(poseb + (size_t)n*Dsz);
            float4 a0 = pp[0], a1 = pp[1], a2 = pp[2], a3 = pp[3];
            float p[16] = {a0.x,a0.y,a0.z,a0.w, a1.x,a1.y,a1.z,a1.w,
                           a2.x,a2.y,a2.z,a2.w, a3.x,a3.y,a3.z,a3.w};
            const int i = tid & 31;
            const int hw = n >> 5, wc = hw % Ssz, hr = hw / Ssz;
            const float chh = (hr+0.5f)*(1.f/Ssz), cww = (wc+0.5f)*(1.f/Ssz);
            const float a = act[(size_t)b*Nsz + n];
            float zz[Csz];
#pragma unroll
            for (int c = 0; c < Csz; ++c) {
                const float* __restrict__ Wi = &Wm[c][i*17];
                float quad = 0.f;
#pragma unroll
                for (int pr = 0; pr < 4; ++pr) {
                    const float4 m4 = *reinterpret_cast<const float4*>(&prm[c][pr*4]);
                    const float4 g4 = *reinterpret_cast<const float4*>(&prm[c][16+pr*4]);
                    float v0 = p[pr*4]*Wi[0] + p[pr*4+1]*Wi[4] + p[pr*4+2]*Wi[8]  + p[pr*4+3]*Wi[12];
                    float v1 = p[pr*4]*Wi[1] + p[pr*4+1]*Wi[5] + p[pr*4+2]*Wi[9]  + p[pr*4+3]*Wi[13];
                    float v2 = p[pr*4]*Wi[2] + p[pr*4+1]*Wi[6] + p[pr*4+2]*Wi[10] + p[pr*4+3]*Wi[14];
                    float v3 = p[pr*4]*Wi[3] + p[pr*4+1]*Wi[7] + p[pr*4+2]*Wi[11] + p[pr*4+3]*Wi[15];
                    if (pr == 0) { v0 += chh; v1 += cww; }
                    const float d0 = v0 - m4.x, d1 = v1 - m4.y, d2 = v2 - m4.z, d3 = v3 - m4.w;
                    quad += d0*d0*g4.x + d1*d1*g4.y + d2*d2*g4.z + d3*d3*g4.w;
                }
                zz[c] = prm[c][32] - quad;
            }
            float zmax = zz[0];
#pragma unroll
            for (int c = 1; c < Csz; ++c) zmax = fmaxf(zmax, zz[c]);
            float zsum = 0.f;
#pragma unroll
            for (int c = 0; c < Csz; ++c) { zz[c] = __expf(zz[c] - zmax); zsum += zz[c]; }
            const float sc = __fdividef(a, zsum);
#pragma unroll
            for (int c = 0; c < Csz; ++c) U2[c*CH + tid] = zz[c]*sc;   // rr
        }
    }
    __syncthreads();

    // ---- M: wave = class; i = lane&31 constant -> W16 hoisted here ----
    {
        const int c = wv_;
        float W16[16];
#pragma unroll
        for (int j = 0; j < 16; ++j) W16[j] = Wm[c][(lane & 31)*17 + j];
        float s0 = 0.f, s1[16], s2[16];
#pragma unroll
        for (int d = 0; d < 16; ++d) { s1[d] = 0.f; s2[d] = 0.f; }
        for (int k = 0; k < CH; k += 64) {
            const int nl = k + lane, n = base + nl;
            if (n < Nsz) {
                const float4* pp = reinterpret_cast<const float4*>(poseb + (size_t)n*Dsz);
                const int hw = n >> 5, wc2 = hw % Ssz, hr2 = hw / Ssz;
                const float chh = (hr2+0.5f)*(1.f/Ssz), cww = (wc2+0.5f)*(1.f/Ssz);
                const float wgt = U2[c*CH + nl];
                s0 += wgt;
#pragma unroll
                for (int pr = 0; pr < 4; ++pr) {
                    const float4 pv = pp[pr];
#pragma unroll
                    for (int r = 0; r < 4; ++r) {
                        float vv = pv.x*W16[r] + pv.y*W16[4+r] + pv.z*W16[8+r] + pv.w*W16[12+r];
                        if (pr == 0 && r == 0) vv += chh;
                        if (pr == 0 && r == 1) vv += cww;
                        const float wvv = wgt*vv;
                        s1[pr*4+r] += wvv;
                        s2[pr*4+r] += wvv*vv;
                    }
                }
            }
        }
        s0 = wave_sum64(s0);
#pragma unroll
        for (int d = 0; d < 16; ++d) { s1[d] = wave_sum64(s1[d]); s2[d] = wave_sum64(s2[d]); }
        if (lane == 63) {
            float* pt = partOut + (size_t)chunk*33*BC + b*Csz + c;
            pt[0] = s0;
#pragma unroll
            for (int d = 0; d < 16; ++d) {
                pt[(size_t)(1+d)*BC]  = s1[d];
                pt[(size_t)(17+d)*BC] = s2[d];
            }
        }
    }
}

// ---------------------------------------------------------------------------
// fin_kernel: thread per (b,c): reduce partials over chunks (coalesced),
// compute mean + o_act (inv_temp=3), write outputs. Validated rounds 1/3.
// ---------------------------------------------------------------------------
__global__ __launch_bounds__(64) void fin_kernel(
    const float* __restrict__ partC, const float* __restrict__ beta_v,
    const float* __restrict__ beta_a, float* __restrict__ out, float inv_temp)
{
    const int bc = blockIdx.x*64 + threadIdx.x;   // grid exact: 640 threads
    const int c = bc % Csz;
    float S[33];
#pragma unroll
    for (int j = 0; j < 33; ++j) S[j] = 0.f;
    for (int ch = 0; ch < NCH; ++ch) {
        const float* pb = partC + (size_t)ch*33*BC + bc;
#pragma unroll
        for (int j = 0; j < 33; ++j) S[j] += pb[(size_t)j*BC];
    }
    const float S0 = S[0], rS0 = 1.f/S0;
    float sumlog = 0.f;
#pragma unroll
    for (int d = 0; d < 16; ++d) {
        const float mn = S[1+d]*rS0;
        const float var = fmaxf(S[17+d]*rS0 - mn*mn, 0.f);
        out[(size_t)bc*Dsz + d] = mn;
        sumlog += __logf(sqrtf(var) + EPSF);
    }
    const float cost = S0*(16.f*beta_v[c] + sumlog);
    out[(size_t)Bsz*Csz*Dsz + bc] = 1.f/(1.f + __expf(-inv_temp*(beta_a[c] - cost)));
}

// ---------------------------------------------------------------------------
// 5 dispatches: memset -> mom -> EM1(fin0+E/M) -> EM2(finC+E/M) -> FIN.
// Workspace: regA/regB = 211200 floats each (1.69 MB, proven budget).
// partM (147456 fl) in regA; partC = regB; partC2 = regA (partM dead by then).
// ---------------------------------------------------------------------------
extern "C" void kernel_launch(void* const* d_in, const int* in_sizes, int n_in,
                              void* d_out, int out_size, void* d_ws, size_t ws_size,
                              hipStream_t stream)
{
    (void)in_sizes; (void)n_in; (void)out_size; (void)ws_size;
    const float* pose = (const float*)d_in[0];
    const float* act  = (const float*)d_in[1];
    const float* w    = (const float*)d_in[2];
    const float* bv   = (const float*)d_in[3];
    const float* ba   = (const float*)d_in[4];
    float* out = (float*)d_out;

    float* regA = (float*)d_ws;                        // 211200 floats
    float* regB = regA + (size_t)NCH*33*BC;            // 211200 floats
    float* partM  = regA;                              // [64][32][72] = 147456 fl
    float* partC  = regB;                              // [10][33][640]
    float* partC2 = regA;                              // aliases partM (dead)

    hipMemsetAsync(partM, 0, (size_t)Bsz*32*MROW*sizeof(float), stream);
    mom_kernel      <<<dim3(Bsz, 2),   640, 0, stream>>>(pose, act, partM);
    em_kernel<true> <<<dim3(Bsz, NCH), 640, 0, stream>>>(pose, act, w, bv, ba, partM, partC, 1.0f);
    em_kernel<false><<<dim3(Bsz, NCH), 640, 0, stream>>>(pose, act, w, bv, ba, partC, partC2, 2.0f);
    fin_kernel      <<<NCH,             64, 0, stream>>>(partC2, bv, ba, out, 3.0f);
}